// Round 2
// baseline (653.891 us; speedup 1.0000x reference)
//
#include <hip/hip_runtime.h>

#define NPTS 65536
#define MM_BLOCKS 64

// ---------------------------------------------------------------------------
// fast tanh: tanh(x) = 1 - 2/(e^{2x}+1). Saturates correctly at +-inf, no NaN.
// v_exp_f32 + v_rcp_f32: ~1e-7 rel err, far below the harness thresholds.
// ---------------------------------------------------------------------------
__device__ __forceinline__ float fast_tanh(float x) {
  float e = __expf(2.0f * x);
  float r = __builtin_amdgcn_rcpf(e + 1.0f);
  return fmaf(-2.0f, r, 1.0f);
}

// ---------------------------------------------------------------------------
// Univariate order-3 jet: value v and directional derivs c1,c2,c3 along a
// fixed direction d.  Through affine: linear.  Through a=tanh(z):
//   a1 = f' z1 ; a2 = f'' z1^2 + f' z2 ; a3 = f''' z1^3 + 3 f'' z1 z2 + f' z3
// with f' = 1-s^2, f'' = -2 s f', f''' = (6 s^2 - 2) f'.
// ---------------------------------------------------------------------------
struct J3 {
  float v, c1, c2, c3;
  __device__ __forceinline__ static J3 seed(float bias) {
    J3 z; z.v = bias; z.c1 = 0.f; z.c2 = 0.f; z.c3 = 0.f; return z;
  }
  __device__ __forceinline__ void macc(float w, const J3& o) {
    v  = fmaf(w, o.v,  v);
    c1 = fmaf(w, o.c1, c1);
    c2 = fmaf(w, o.c2, c2);
    c3 = fmaf(w, o.c3, c3);
  }
  __device__ __forceinline__ J3 chain() const {
    float s    = fast_tanh(v);
    float fp   = fmaf(-s, s, 1.0f);             // 1 - s^2
    float fpp  = -2.0f * s * fp;                // -2 s (1-s^2)
    float fppp = fmaf(6.0f * s, s, -2.0f) * fp; // (6 s^2 - 2)(1 - s^2)
    J3 r;
    r.v  = s;
    r.c1 = fp * c1;
    r.c2 = fmaf(fpp, c1 * c1, fp * c2);
    r.c3 = fmaf(fppp * c1, c1 * c1, fmaf(3.0f * fpp, c1 * c2, fp * c3));
    return r;
  }
};

// ---------------------------------------------------------------------------
// Order-3 jet along direction D PLUS a mixed t-leg:
//   t = d psi/dt (dir B), m = d^2 psi / dD dt.
// Linear layers: all 6 components linear.  Through a=tanh(z):
//   r.t = f' t ;  r.m = f'' c1 t + f' m   (exactly the JM recurrence,
// riding on the same s/f'/f''/f''' chain as J3 -> merges the old JM passes
// into the PX/PY passes, 6 net evals -> 4).
// ---------------------------------------------------------------------------
struct J3t {
  float v, c1, c2, c3, t, m;
  __device__ __forceinline__ static J3t seed(float bias) {
    J3t z; z.v = bias; z.c1 = 0.f; z.c2 = 0.f; z.c3 = 0.f; z.t = 0.f; z.m = 0.f;
    return z;
  }
  __device__ __forceinline__ void macc(float w, const J3t& o) {
    v  = fmaf(w, o.v,  v);
    c1 = fmaf(w, o.c1, c1);
    c2 = fmaf(w, o.c2, c2);
    c3 = fmaf(w, o.c3, c3);
    t  = fmaf(w, o.t,  t);
    m  = fmaf(w, o.m,  m);
  }
  __device__ __forceinline__ J3t chain() const {
    float s    = fast_tanh(v);
    float fp   = fmaf(-s, s, 1.0f);
    float fpp  = -2.0f * s * fp;
    float fppp = fmaf(6.0f * s, s, -2.0f) * fp;
    J3t r;
    r.v  = s;
    r.c1 = fp * c1;
    r.c2 = fmaf(fpp, c1 * c1, fp * c2);
    r.c3 = fmaf(fppp * c1, c1 * c1, fmaf(3.0f * fpp, c1 * c2, fp * c3));
    r.t  = fp * t;
    r.m  = fmaf(fpp, c1 * t, fp * m);
    return r;
  }
};

// ---------------------------------------------------------------------------
// One dense layer + tanh over a jet type.  WT is TRANSPOSED in LDS
// (WT[j*DIN + i] = W[i][j]) so the unrolled i-loop reads consecutive floats
// (compiler merges into ds_read_b128; wave-uniform address = free broadcast).
// ---------------------------------------------------------------------------
template <class J, int DIN, int DOUT>
__device__ __forceinline__ void layerT(const float* __restrict__ WT,
                                       const float* __restrict__ bias,
                                       const J* in, J* out) {
#pragma unroll
  for (int j = 0; j < DOUT; ++j) {
    J z = J::seed(bias[j]);
#pragma unroll
    for (int i = 0; i < DIN; ++i) z.macc(WT[j * DIN + i], in[i]);
    out[j] = z.chain();
  }
}

// LDS layout (floats): L0 W@0(9) b@9(3) | L1 W@12(60) b@72(20)
// | L2..L6 stride 420: W@92+420l(400) b@+400(20) | L7 W@2192(40) b@2232(2)
#define LDS_W_FLOATS 2234

template <class J>
__device__ __forceinline__ void run_net(const float* __restrict__ w, J* A, J* O) {
  J B[20];
  layerT<J, 3, 3>(w + 0, w + 9, A, B);
  layerT<J, 3, 20>(w + 12, w + 72, B, A);
#pragma unroll 1
  for (int l = 0; l < 5; ++l) {   // keep rolled: hot body stays in I-cache
    const float* Wl = w + 92 + l * 420;
    layerT<J, 20, 20>(Wl, Wl + 400, A, B);
#pragma unroll
    for (int jj = 0; jj < 20; ++jj) A[jj] = B[jj];
  }
  layerT<J, 20, 2>(w + 2192, w + 2232, A, O);
}

// ---------------------------------------------------------------------------
// min/max of X[:,0] via monotone-uint keys.  mm_reduce writes one partial
// (kmin,kmax) pair per block -- no init kernel, no atomics.  pinn_main
// butterfly-reduces the 64 partials per wave (lane l holds partial l).
// ---------------------------------------------------------------------------
__device__ __forceinline__ unsigned flipk(float f) {
  unsigned u = __float_as_uint(f);
  return (u & 0x80000000u) ? ~u : (u | 0x80000000u);
}
__device__ __forceinline__ float unflip(unsigned k) {
  unsigned u = (k & 0x80000000u) ? (k ^ 0x80000000u) : ~k;
  return __uint_as_float(u);
}

__global__ void __launch_bounds__(256) mm_reduce(const float* __restrict__ X,
                                                 unsigned* __restrict__ mm) {
  __shared__ unsigned smin[4], smax[4];
  unsigned kmin = 0xFFFFFFFFu, kmax = 0u;
  for (int i = blockIdx.x * 256 + threadIdx.x; i < NPTS; i += gridDim.x * 256) {
    unsigned key = flipk(X[3 * i]);
    kmin = min(kmin, key);
    kmax = max(kmax, key);
  }
#pragma unroll
  for (int o = 32; o > 0; o >>= 1) {
    kmin = min(kmin, (unsigned)__shfl_down((int)kmin, o, 64));
    kmax = max(kmax, (unsigned)__shfl_down((int)kmax, o, 64));
  }
  int wv = threadIdx.x >> 6;
  if ((threadIdx.x & 63) == 0) { smin[wv] = kmin; smax[wv] = kmax; }
  __syncthreads();
  if (threadIdx.x == 0) {
    kmin = min(min(smin[0], smin[1]), min(smin[2], smin[3]));
    kmax = max(max(smax[0], smax[1]), max(smax[2], smax[3]));
    mm[2 * blockIdx.x + 0] = kmin;
    mm[2 * blockIdx.x + 1] = kmax;
  }
}

// ---------------------------------------------------------------------------
// Main kernel: one thread per point, 4 sequential jet passes (was 6):
//   J3t d=(k,0,0), t-leg:  psi_x, psi_xx, psi_xxx, psi_xt, p, p_x
//   J3t d=(0,k,0), t-leg:  psi_y, psi_yy, psi_yyy, psi_yt, p_y
//   J3  d=(k,k,0):  S2p = xx+2xy+yy,  S3p = xxx+3xxy+3xyy+yyy
//   J3  d=(k,-k,0): S2m = xx-2xy+yy,  S3m = xxx-3xxy+3xyy-yyy
// Sequential passes keep ONE unrolled body hot in I-cache at a time (the
// round-1 pass-parallel variant with 6 concurrent code regions regressed).
// __launch_bounds__(256,1): grid caps occupancy at 1 wave/SIMD anyway
// (65536 threads = 1024 waves), so let the allocator use >256 VGPRs and hold
// the J3t double-buffer (240 floats) fully in registers -- no scratch spills
// (round 0 at the 256-VGPR cap spilled ~2.7 MB).
// ---------------------------------------------------------------------------
__global__ void __launch_bounds__(256, 1) pinn_main(
    const float* __restrict__ X,
    const float* W1, const float* b1, const float* W2, const float* b2,
    const float* W3, const float* b3, const float* W4, const float* b4,
    const float* W5, const float* b5, const float* W6, const float* b6,
    const float* W7, const float* b7, const float* W8, const float* b8,
    const float* lam1p, const float* lam2p, const unsigned* __restrict__ mm,
    float* __restrict__ out) {
  __shared__ float w[LDS_W_FLOATS];
  {
    const float* Wsrc[8] = {W1, W2, W3, W4, W5, W6, W7, W8};
    const float* bsrc[8] = {b1, b2, b3, b4, b5, b6, b7, b8};
    const int dinA[8]  = {3, 3, 20, 20, 20, 20, 20, 20};
    const int doutA[8] = {3, 20, 20, 20, 20, 20, 20, 2};
    const int offW[8]  = {0, 12, 92, 512, 932, 1352, 1772, 2192};
    const int offB[8]  = {9, 72, 492, 912, 1332, 1752, 2172, 2232};
#pragma unroll
    for (int a = 0; a < 8; ++a) {
      const int din = dinA[a], dout = doutA[a], nw = din * dout;
      for (int s = threadIdx.x; s < nw; s += 256) {
        int row = s / dout, col = s % dout;  // compile-time dout -> magic mul
        w[offW[a] + col * din + row] = Wsrc[a][s];  // transposed store
      }
      for (int s = threadIdx.x; s < dout; s += 256) w[offB[a] + s] = bsrc[a][s];
    }
  }

  const int lane = threadIdx.x & 63;
  const int gid  = blockIdx.x * 256 + threadIdx.x;

  // global min/max: lane l holds block-partial l, butterfly across the wave
  unsigned pmin = mm[2 * lane + 0];
  unsigned pmax = mm[2 * lane + 1];
#pragma unroll
  for (int o = 1; o < 64; o <<= 1) {
    pmin = min(pmin, (unsigned)__shfl_xor((int)pmin, o, 64));
    pmax = max(pmax, (unsigned)__shfl_xor((int)pmax, o, 64));
  }
  float lb = unflip(pmin);
  float ub = unflip(pmax);
  float kk = 2.0f / (ub - lb);

  float x = X[3 * gid], y = X[3 * gid + 1], tt = X[3 * gid + 2];
  float h0 = fmaf(kk, x - lb, -1.0f);
  float h1 = fmaf(kk, y - lb, -1.0f);
  float h2 = fmaf(kk, tt - lb, -1.0f);

  __syncthreads();  // weights staged

  float psi_x = 0, psi_xx = 0, psi_xxx = 0, psi_xt = 0, p_val = 0, p_x = 0;
  float psi_y = 0, psi_yy = 0, psi_yyy = 0, psi_yt = 0, p_y = 0;

  // passes 1-2: J3t (x-dir + t leg, then y-dir + t leg)
#pragma unroll 1
  for (int ph = 0; ph < 2; ++ph) {
    J3t A[20], O[2];
    float dx = ph ? 0.0f : kk;
    float dy = ph ? kk : 0.0f;
    A[0].v = h0; A[0].c1 = dx;  A[0].c2 = 0.f; A[0].c3 = 0.f; A[0].t = 0.f; A[0].m = 0.f;
    A[1].v = h1; A[1].c1 = dy;  A[1].c2 = 0.f; A[1].c3 = 0.f; A[1].t = 0.f; A[1].m = 0.f;
    A[2].v = h2; A[2].c1 = 0.f; A[2].c2 = 0.f; A[2].c3 = 0.f; A[2].t = kk;  A[2].m = 0.f;
    run_net<J3t>(w, A, O);
    if (ph == 0) {
      psi_x = O[0].c1; psi_xx = O[0].c2; psi_xxx = O[0].c3; psi_xt = O[0].m;
      p_val = O[1].v;  p_x = O[1].c1;
    } else {
      psi_y = O[0].c1; psi_yy = O[0].c2; psi_yyy = O[0].c3; psi_yt = O[0].m;
      p_y = O[1].c1;
    }
  }

  // passes 3-4: plain J3 along (k,k,0) and (k,-k,0)
  float S2p = 0, S3p = 0, S2m = 0, S3m = 0;
#pragma unroll 1
  for (int ph = 0; ph < 2; ++ph) {
    J3 A[20], O[2];
    float dy = ph ? -kk : kk;
    A[0].v = h0; A[0].c1 = kk;  A[0].c2 = 0.f; A[0].c3 = 0.f;
    A[1].v = h1; A[1].c1 = dy;  A[1].c2 = 0.f; A[1].c3 = 0.f;
    A[2].v = h2; A[2].c1 = 0.f; A[2].c2 = 0.f; A[2].c3 = 0.f;
    run_net<J3>(w, A, O);
    if (ph == 0) { S2p = O[0].c2; S3p = O[0].c3; }
    else         { S2m = O[0].c2; S3m = O[0].c3; }
  }

  // polarization identities
  float psi_xy  = 0.25f * (S2p - S2m);
  float psi_xxy = (S3p - S3m - 2.0f * psi_yyy) * (1.0f / 6.0f);
  float psi_xyy = (S3p + S3m - 2.0f * psi_xxx) * (1.0f / 6.0f);

  float u = psi_y, vv = -psi_x;
  float u_x = psi_xy,  u_y = psi_yy,  u_t = psi_yt;
  float v_x = -psi_xx, v_y = -psi_xy, v_t = -psi_xt;
  float u_xx = psi_xxy,  u_yy = psi_yyy;
  float v_xx = -psi_xxx, v_yy = -psi_xyy;

  float lam1 = lam1p[0], lam2 = lam2p[0];
  float f_u = u_t + lam1 * (u * u_x + vv * u_y) + p_x - lam2 * (u_xx + u_yy);
  float f_v = v_t + lam1 * (u * v_x + vv * v_y) + p_y - lam2 * (v_xx + v_yy);

  out[gid] = u;
  out[NPTS + gid] = vv;
  out[2 * NPTS + gid] = p_val;
  out[3 * NPTS + gid] = f_u;
  out[4 * NPTS + gid] = f_v;
}

extern "C" void kernel_launch(void* const* d_in, const int* in_sizes, int n_in,
                              void* d_out, int out_size, void* d_ws, size_t ws_size,
                              hipStream_t stream) {
  (void)in_sizes; (void)n_in; (void)out_size; (void)ws_size;
  const float* X = (const float*)d_in[0];
  const float* W[8]; const float* B[8];
  for (int i = 0; i < 8; ++i) {
    W[i] = (const float*)d_in[1 + 2 * i];
    B[i] = (const float*)d_in[2 + 2 * i];
  }
  const float* lam1 = (const float*)d_in[17];
  const float* lam2 = (const float*)d_in[18];
  unsigned* mm = (unsigned*)d_ws;
  float* out = (float*)d_out;

  hipLaunchKernelGGL(mm_reduce, dim3(MM_BLOCKS), dim3(256), 0, stream, X, mm);
  hipLaunchKernelGGL(pinn_main, dim3(NPTS / 256), dim3(256), 0, stream,
                     X, W[0], B[0], W[1], B[1], W[2], B[2], W[3], B[3],
                     W[4], B[4], W[5], B[5], W[6], B[6], W[7], B[7],
                     lam1, lam2, mm, out);
}

// Round 3
// 529.131 us; speedup vs baseline: 1.2358x; 1.2358x over previous
//
#include <hip/hip_runtime.h>

#define NPTS 65536
#define MM_BLOCKS 64

// ---------------------------------------------------------------------------
// fast tanh: tanh(x) = 1 - 2/(e^{2x}+1). Saturates correctly at +-inf, no NaN.
// ---------------------------------------------------------------------------
__device__ __forceinline__ float fast_tanh(float x) {
  float e = __expf(2.0f * x);
  float r = __builtin_amdgcn_rcpf(e + 1.0f);
  return fmaf(-2.0f, r, 1.0f);
}

// ---------------------------------------------------------------------------
// Univariate order-3 jet (4 components -- the max that fits registers, per
// round-2 spill disaster: 6-comp jets => 1.5 GB scratch traffic).
// ---------------------------------------------------------------------------
struct J3 {
  float v, c1, c2, c3;
  __device__ __forceinline__ static J3 seed(float bias) {
    J3 z; z.v = bias; z.c1 = 0.f; z.c2 = 0.f; z.c3 = 0.f; return z;
  }
  __device__ __forceinline__ void macc(float w, const J3& o) {
    v  = fmaf(w, o.v,  v);
    c1 = fmaf(w, o.c1, c1);
    c2 = fmaf(w, o.c2, c2);
    c3 = fmaf(w, o.c3, c3);
  }
  __device__ __forceinline__ J3 chain() const {
    float s    = fast_tanh(v);
    float fp   = fmaf(-s, s, 1.0f);             // 1 - s^2
    float fpp  = -2.0f * s * fp;                // -2 s (1-s^2)
    float fppp = fmaf(6.0f * s, s, -2.0f) * fp; // (6 s^2 - 2)(1 - s^2)
    J3 r;
    r.v  = s;
    r.c1 = fp * c1;
    r.c2 = fmaf(fpp, c1 * c1, fp * c2);
    r.c3 = fmaf(fppp * c1, c1 * c1, fmaf(3.0f * fpp, c1 * c2, fp * c3));
    return r;
  }
};

// ---------------------------------------------------------------------------
// Mixed second-order jet: value v, first derivs a (dir A), b (dir B), mixed m.
// ---------------------------------------------------------------------------
struct JM {
  float v, a, b, m;
  __device__ __forceinline__ static JM seed(float bias) {
    JM z; z.v = bias; z.a = 0.f; z.b = 0.f; z.m = 0.f; return z;
  }
  __device__ __forceinline__ void macc(float w, const JM& o) {
    v = fmaf(w, o.v, v);
    a = fmaf(w, o.a, a);
    b = fmaf(w, o.b, b);
    m = fmaf(w, o.m, m);
  }
  __device__ __forceinline__ JM chain() const {
    float s   = fast_tanh(v);
    float fp  = fmaf(-s, s, 1.0f);
    float fpp = -2.0f * s * fp;
    JM r;
    r.v = s;
    r.a = fp * a;
    r.b = fp * b;
    r.m = fmaf(fpp, a * b, fp * m);
    return r;
  }
};

// ---------------------------------------------------------------------------
// One dense layer + tanh over a jet type.  WT TRANSPOSED in LDS so the
// unrolled i-loop reads consecutive floats (ds_read_b128, wave-uniform
// address = broadcast).
// ---------------------------------------------------------------------------
template <class J, int DIN, int DOUT>
__device__ __forceinline__ void layerT(const float* __restrict__ WT,
                                       const float* __restrict__ bias,
                                       const J* in, J* out) {
#pragma unroll
  for (int j = 0; j < DOUT; ++j) {
    J z = J::seed(bias[j]);
#pragma unroll
    for (int i = 0; i < DIN; ++i) z.macc(WT[j * DIN + i], in[i]);
    out[j] = z.chain();
  }
}

// LDS layout (floats): L0 W@0(9) b@9(3) | L1 W@12(60) b@72(20)
// | L2..L6 stride 420: W@92+420l(400) b@+400(20) | L7 W@2192(40) b@2232(2)
#define LDS_W_FLOATS 2234

// Explicit ping-pong (no A<-B copy-backs, ~5% fewer instructions than the
// rolled copy variant).  Net: L1 A->B, L2 B->A, {L3 A->B, L4 B->A} x2 rolled,
// L7 A->B, L8 B->O.
template <class J>
__device__ __forceinline__ void run_net(const float* __restrict__ w, J* A, J* O) {
  J B[20];
  layerT<J, 3, 3>(w + 0, w + 9, A, B);
  layerT<J, 3, 20>(w + 12, w + 72, B, A);
#pragma unroll 1
  for (int l = 0; l < 2; ++l) {   // keep rolled: hot body stays in I-cache
    const float* Wl = w + 92 + l * 840;
    layerT<J, 20, 20>(Wl, Wl + 400, A, B);
    layerT<J, 20, 20>(Wl + 420, Wl + 820, B, A);
  }
  layerT<J, 20, 20>(w + 1772, w + 2172, A, B);
  layerT<J, 20, 2>(w + 2192, w + 2232, B, O);
}

// ---------------------------------------------------------------------------
// min/max of X[:,0] via monotone-uint keys; one partial pair per block,
// butterfly-reduced per wave inside pinn_main.
// ---------------------------------------------------------------------------
__device__ __forceinline__ unsigned flipk(float f) {
  unsigned u = __float_as_uint(f);
  return (u & 0x80000000u) ? ~u : (u | 0x80000000u);
}
__device__ __forceinline__ float unflip(unsigned k) {
  unsigned u = (k & 0x80000000u) ? (k ^ 0x80000000u) : ~k;
  return __uint_as_float(u);
}

__global__ void __launch_bounds__(256) mm_reduce(const float* __restrict__ X,
                                                 unsigned* __restrict__ mm) {
  __shared__ unsigned smin[4], smax[4];
  unsigned kmin = 0xFFFFFFFFu, kmax = 0u;
  for (int i = blockIdx.x * 256 + threadIdx.x; i < NPTS; i += gridDim.x * 256) {
    unsigned key = flipk(X[3 * i]);
    kmin = min(kmin, key);
    kmax = max(kmax, key);
  }
#pragma unroll
  for (int o = 32; o > 0; o >>= 1) {
    kmin = min(kmin, (unsigned)__shfl_down((int)kmin, o, 64));
    kmax = max(kmax, (unsigned)__shfl_down((int)kmax, o, 64));
  }
  int wv = threadIdx.x >> 6;
  if ((threadIdx.x & 63) == 0) { smin[wv] = kmin; smax[wv] = kmax; }
  __syncthreads();
  if (threadIdx.x == 0) {
    kmin = min(min(smin[0], smin[1]), min(smin[2], smin[3]));
    kmax = max(max(smax[0], smax[1]), max(smax[2], smax[3]));
    mm[2 * blockIdx.x + 0] = kmin;
    mm[2 * blockIdx.x + 1] = kmax;
  }
}

// ---------------------------------------------------------------------------
// Main kernel: TWO THREADS PER POINT, identical code path for every thread
// (pass seeds are DATA selected by lane parity q -- no divergence, one code
// region hot at a time; round 1 showed 6 concurrent regions thrash I-cache,
// round 2 showed 6-comp jets spill).  Each thread: 3 sequential 4-comp
// passes (half of round 0's 6), thread count 2x => 2048 waves = 2/SIMD,
// hiding the trans-pipe/LDS-broadcast stalls behind a second wave.
//   q=0: J3 d=(k,0,0) -> psi_x,psi_xx,psi_xxx,p,p_x; J3 d=(k,k,0) -> S2p,S3p;
//        JM a=x,b=t -> psi_xt
//   q=1: J3 d=(0,k,0) -> psi_y,psi_yy,psi_yyy,p_y;   J3 d=(k,-k,0) -> S2m,S3m;
//        JM a=y,b=t -> psi_yt
// Pair combine: 7 shfl_xor(...,1), even lane assembles + stores.
// ---------------------------------------------------------------------------
__global__ void __launch_bounds__(256, 2) pinn_main(
    const float* __restrict__ X,
    const float* W1, const float* b1, const float* W2, const float* b2,
    const float* W3, const float* b3, const float* W4, const float* b4,
    const float* W5, const float* b5, const float* W6, const float* b6,
    const float* W7, const float* b7, const float* W8, const float* b8,
    const float* lam1p, const float* lam2p, const unsigned* __restrict__ mm,
    float* __restrict__ out) {
  __shared__ float w[LDS_W_FLOATS];
  {
    const float* Wsrc[8] = {W1, W2, W3, W4, W5, W6, W7, W8};
    const float* bsrc[8] = {b1, b2, b3, b4, b5, b6, b7, b8};
    const int dinA[8]  = {3, 3, 20, 20, 20, 20, 20, 20};
    const int doutA[8] = {3, 20, 20, 20, 20, 20, 20, 2};
    const int offW[8]  = {0, 12, 92, 512, 932, 1352, 1772, 2192};
    const int offB[8]  = {9, 72, 492, 912, 1332, 1752, 2172, 2232};
#pragma unroll
    for (int a = 0; a < 8; ++a) {
      const int din = dinA[a], dout = doutA[a], nw = din * dout;
      for (int s = threadIdx.x; s < nw; s += 256) {
        int row = s / dout, col = s % dout;  // compile-time dout -> magic mul
        w[offW[a] + col * din + row] = Wsrc[a][s];  // transposed store
      }
      for (int s = threadIdx.x; s < dout; s += 256) w[offB[a] + s] = bsrc[a][s];
    }
  }

  const int lane = threadIdx.x & 63;
  const int gid  = blockIdx.x * 256 + threadIdx.x;
  const int pt   = gid >> 1;          // point index (two lanes per point)
  const int q    = gid & 1;           // 0: x-family, 1: y-family

  // global min/max: lane l holds block-partial l, butterfly across the wave
  unsigned pmin = mm[2 * lane + 0];
  unsigned pmax = mm[2 * lane + 1];
#pragma unroll
  for (int o = 1; o < 64; o <<= 1) {
    pmin = min(pmin, (unsigned)__shfl_xor((int)pmin, o, 64));
    pmax = max(pmax, (unsigned)__shfl_xor((int)pmax, o, 64));
  }
  float lb = unflip(pmin);
  float ub = unflip(pmax);
  float kk = 2.0f / (ub - lb);

  float x = X[3 * pt], y = X[3 * pt + 1], tt = X[3 * pt + 2];
  float h0 = fmaf(kk, x - lb, -1.0f);
  float h1 = fmaf(kk, y - lb, -1.0f);
  float h2 = fmaf(kk, tt - lb, -1.0f);

  __syncthreads();  // weights staged

  // pass-A / pass-B first-deriv seeds, parity-selected (cndmask, no branch)
  float a0 = q ? 0.0f : kk, a1 = q ? kk : 0.0f;   // pass A: x-dir / y-dir
  float b1s = q ? -kk : kk;                        // pass B: (k,+-k,0)

  float rc1 = 0, rc2 = 0, rc3 = 0, rpv = 0, rpc = 0;  // pass A results
  float s2 = 0, s3 = 0;                                // pass B results

#pragma unroll 1
  for (int ph = 0; ph < 2; ++ph) {
    J3 A[20], O[2];
    float d0 = ph ? kk  : a0;
    float d1 = ph ? b1s : a1;
    A[0].v = h0; A[0].c1 = d0;  A[0].c2 = 0.f; A[0].c3 = 0.f;
    A[1].v = h1; A[1].c1 = d1;  A[1].c2 = 0.f; A[1].c3 = 0.f;
    A[2].v = h2; A[2].c1 = 0.f; A[2].c2 = 0.f; A[2].c3 = 0.f;
    run_net<J3>(w, A, O);
    if (ph == 0) {
      rc1 = O[0].c1; rc2 = O[0].c2; rc3 = O[0].c3;
      rpv = O[1].v;  rpc = O[1].c1;
    } else {
      s2 = O[0].c2; s3 = O[0].c3;
    }
  }

  float rm;
  {
    JM A[20], O[2];
    A[0].v = h0; A[0].a = a0;  A[0].b = 0.f; A[0].m = 0.f;
    A[1].v = h1; A[1].a = a1;  A[1].b = 0.f; A[1].m = 0.f;
    A[2].v = h2; A[2].a = 0.f; A[2].b = kk;  A[2].m = 0.f;
    run_net<JM>(w, A, O);
    rm = O[0].m;   // psi_xt (q=0) / psi_yt (q=1)
  }

  // pair exchange: even lane receives the y-family values
  float psi_y   = __shfl_xor(rc1, 1, 64);
  float psi_yy  = __shfl_xor(rc2, 1, 64);
  float psi_yyy = __shfl_xor(rc3, 1, 64);
  float p_y     = __shfl_xor(rpc, 1, 64);
  float S2m     = __shfl_xor(s2, 1, 64);
  float S3m     = __shfl_xor(s3, 1, 64);
  float psi_yt  = __shfl_xor(rm, 1, 64);

  if (q == 0) {
    float psi_x = rc1, psi_xx = rc2, psi_xxx = rc3;
    float p_val = rpv, p_x = rpc;
    float S2p = s2, S3p = s3;
    float psi_xt = rm;

    // polarization identities
    float psi_xy  = 0.25f * (S2p - S2m);
    float psi_xxy = (S3p - S3m - 2.0f * psi_yyy) * (1.0f / 6.0f);
    float psi_xyy = (S3p + S3m - 2.0f * psi_xxx) * (1.0f / 6.0f);

    float u = psi_y, vv = -psi_x;
    float u_x = psi_xy,  u_y = psi_yy,  u_t = psi_yt;
    float v_x = -psi_xx, v_y = -psi_xy, v_t = -psi_xt;
    float u_xx = psi_xxy,  u_yy = psi_yyy;
    float v_xx = -psi_xxx, v_yy = -psi_xyy;

    float lam1 = lam1p[0], lam2 = lam2p[0];
    float f_u = u_t + lam1 * (u * u_x + vv * u_y) + p_x - lam2 * (u_xx + u_yy);
    float f_v = v_t + lam1 * (u * v_x + vv * v_y) + p_y - lam2 * (v_xx + v_yy);

    out[pt] = u;
    out[NPTS + pt] = vv;
    out[2 * NPTS + pt] = p_val;
    out[3 * NPTS + pt] = f_u;
    out[4 * NPTS + pt] = f_v;
  }
}

extern "C" void kernel_launch(void* const* d_in, const int* in_sizes, int n_in,
                              void* d_out, int out_size, void* d_ws, size_t ws_size,
                              hipStream_t stream) {
  (void)in_sizes; (void)n_in; (void)out_size; (void)ws_size;
  const float* X = (const float*)d_in[0];
  const float* W[8]; const float* B[8];
  for (int i = 0; i < 8; ++i) {
    W[i] = (const float*)d_in[1 + 2 * i];
    B[i] = (const float*)d_in[2 + 2 * i];
  }
  const float* lam1 = (const float*)d_in[17];
  const float* lam2 = (const float*)d_in[18];
  unsigned* mm = (unsigned*)d_ws;
  float* out = (float*)d_out;

  hipLaunchKernelGGL(mm_reduce, dim3(MM_BLOCKS), dim3(256), 0, stream, X, mm);
  hipLaunchKernelGGL(pinn_main, dim3(2 * NPTS / 256), dim3(256), 0, stream,
                     X, W[0], B[0], W[1], B[1], W[2], B[2], W[3], B[3],
                     W[4], B[4], W[5], B[5], W[6], B[6], W[7], B[7],
                     lam1, lam2, mm, out);
}

// Round 4
// 405.792 us; speedup vs baseline: 1.6114x; 1.3039x over previous
//
#include <hip/hip_runtime.h>

#define NPTS 65536
#define MM_BLOCKS 64

// ---------------------------------------------------------------------------
// fast tanh: tanh(x) = 1 - 2/(e^{2x}+1). Saturates correctly at +-inf, no NaN.
// ---------------------------------------------------------------------------
__device__ __forceinline__ float fast_tanh(float x) {
  float e = __expf(2.0f * x);
  float r = __builtin_amdgcn_rcpf(e + 1.0f);
  return fmaf(-2.0f, r, 1.0f);
}

// ---------------------------------------------------------------------------
// Univariate order-3 jet (4 components -- the max that fits registers; the
// 6-comp variant in round 2 spilled 1.5 GB).
// ---------------------------------------------------------------------------
struct J3 {
  float v, c1, c2, c3;
  __device__ __forceinline__ static J3 seed(float bias) {
    J3 z; z.v = bias; z.c1 = 0.f; z.c2 = 0.f; z.c3 = 0.f; return z;
  }
  __device__ __forceinline__ void macc(float w, const J3& o) {
    v  = fmaf(w, o.v,  v);
    c1 = fmaf(w, o.c1, c1);
    c2 = fmaf(w, o.c2, c2);
    c3 = fmaf(w, o.c3, c3);
  }
  __device__ __forceinline__ J3 chain() const {
    float s    = fast_tanh(v);
    float fp   = fmaf(-s, s, 1.0f);             // 1 - s^2
    float fpp  = -2.0f * s * fp;                // -2 s (1-s^2)
    float fppp = fmaf(6.0f * s, s, -2.0f) * fp; // (6 s^2 - 2)(1 - s^2)
    J3 r;
    r.v  = s;
    r.c1 = fp * c1;
    r.c2 = fmaf(fpp, c1 * c1, fp * c2);
    r.c3 = fmaf(fppp * c1, c1 * c1, fmaf(3.0f * fpp, c1 * c2, fp * c3));
    return r;
  }
};

// ---------------------------------------------------------------------------
// Mixed second-order jet: value v, first derivs a (dir A), b (dir B), mixed m.
// ---------------------------------------------------------------------------
struct JM {
  float v, a, b, m;
  __device__ __forceinline__ static JM seed(float bias) {
    JM z; z.v = bias; z.a = 0.f; z.b = 0.f; z.m = 0.f; return z;
  }
  __device__ __forceinline__ void macc(float w, const JM& o) {
    v = fmaf(w, o.v, v);
    a = fmaf(w, o.a, a);
    b = fmaf(w, o.b, b);
    m = fmaf(w, o.m, m);
  }
  __device__ __forceinline__ JM chain() const {
    float s   = fast_tanh(v);
    float fp  = fmaf(-s, s, 1.0f);
    float fpp = -2.0f * s * fp;
    JM r;
    r.v = s;
    r.a = fp * a;
    r.b = fp * b;
    r.m = fmaf(fpp, a * b, fp * m);
    return r;
  }
};

// ---------------------------------------------------------------------------
// One dense layer + tanh over a jet type.  WT TRANSPOSED in LDS so the
// unrolled i-loop reads consecutive floats (ds_read_b128, wave-uniform
// address = broadcast).
// ---------------------------------------------------------------------------
template <class J, int DIN, int DOUT>
__device__ __forceinline__ void layerT(const float* __restrict__ WT,
                                       const float* __restrict__ bias,
                                       const J* in, J* out) {
#pragma unroll
  for (int j = 0; j < DOUT; ++j) {
    J z = J::seed(bias[j]);
#pragma unroll
    for (int i = 0; i < DIN; ++i) z.macc(WT[j * DIN + i], in[i]);
    out[j] = z.chain();
  }
}

// LDS layout (floats): L0 W@0(9) b@9(3) | L1 W@12(60) b@72(20)
// | L2..L6 stride 420: W@92+420l(400) b@+400(20) | L7 W@2192(40) b@2232(2)
#define LDS_W_FLOATS 2234

// Explicit ping-pong (no A<-B copy-backs).  Net: L1 A->B, L2 B->A,
// {L3 A->B, L4 B->A} x2 rolled, L7 A->B, L8 B->O.
template <class J>
__device__ __forceinline__ void run_net(const float* __restrict__ w, J* A, J* O) {
  J B[20];
  layerT<J, 3, 3>(w + 0, w + 9, A, B);
  layerT<J, 3, 20>(w + 12, w + 72, B, A);
#pragma unroll 1
  for (int l = 0; l < 2; ++l) {   // keep rolled: hot body stays in I-cache
    const float* Wl = w + 92 + l * 840;
    layerT<J, 20, 20>(Wl, Wl + 400, A, B);
    layerT<J, 20, 20>(Wl + 420, Wl + 820, B, A);
  }
  layerT<J, 20, 20>(w + 1772, w + 2172, A, B);
  layerT<J, 20, 2>(w + 2192, w + 2232, B, O);
}

// ---------------------------------------------------------------------------
// min/max of X[:,0] via monotone-uint keys; one partial pair per block,
// butterfly-reduced per wave inside pinn_main.
// ---------------------------------------------------------------------------
__device__ __forceinline__ unsigned flipk(float f) {
  unsigned u = __float_as_uint(f);
  return (u & 0x80000000u) ? ~u : (u | 0x80000000u);
}
__device__ __forceinline__ float unflip(unsigned k) {
  unsigned u = (k & 0x80000000u) ? (k ^ 0x80000000u) : ~k;
  return __uint_as_float(u);
}

__global__ void __launch_bounds__(256) mm_reduce(const float* __restrict__ X,
                                                 unsigned* __restrict__ mm) {
  __shared__ unsigned smin[4], smax[4];
  unsigned kmin = 0xFFFFFFFFu, kmax = 0u;
  for (int i = blockIdx.x * 256 + threadIdx.x; i < NPTS; i += gridDim.x * 256) {
    unsigned key = flipk(X[3 * i]);
    kmin = min(kmin, key);
    kmax = max(kmax, key);
  }
#pragma unroll
  for (int o = 32; o > 0; o >>= 1) {
    kmin = min(kmin, (unsigned)__shfl_down((int)kmin, o, 64));
    kmax = max(kmax, (unsigned)__shfl_down((int)kmax, o, 64));
  }
  int wv = threadIdx.x >> 6;
  if ((threadIdx.x & 63) == 0) { smin[wv] = kmin; smax[wv] = kmax; }
  __syncthreads();
  if (threadIdx.x == 0) {
    kmin = min(min(smin[0], smin[1]), min(smin[2], smin[3]));
    kmax = max(max(smax[0], smax[1]), max(smax[2], smax[3]));
    mm[2 * blockIdx.x + 0] = kmin;
    mm[2 * blockIdx.x + 1] = kmax;
  }
}

// ---------------------------------------------------------------------------
// Main kernel: TWO THREADS PER POINT, identical code path for every thread
// (pass seeds are DATA selected by lane parity q -- no divergence).  Each
// thread runs 3 sequential 4-comp passes; 2048 waves = 2 waves/SIMD.
// PLAIN __launch_bounds__(256): empirically yields a 256-VGPR cap (round 0),
// which both fits the jet double-buffer (no spills) AND permits 2 waves/SIMD
// (pool = 512/SIMD).  (256,2) wrongly capped at 128 VGPR -> 1 GB spills
// (round 3); (256,1) allowed 6-comp jets to blow past 256 -> 1.5 GB spills
// (round 2).  Do not add a second launch_bounds argument.
//   q=0: J3 d=(k,0,0) -> psi_x,psi_xx,psi_xxx,p,p_x; J3 d=(k,k,0) -> S2p,S3p;
//        JM a=x,b=t -> psi_xt
//   q=1: J3 d=(0,k,0) -> psi_y,psi_yy,psi_yyy,p_y;   J3 d=(k,-k,0) -> S2m,S3m;
//        JM a=y,b=t -> psi_yt
// Pair combine: 7 shfl_xor(...,1), even lane assembles + stores.
// ---------------------------------------------------------------------------
__global__ void __launch_bounds__(256) pinn_main(
    const float* __restrict__ X,
    const float* W1, const float* b1, const float* W2, const float* b2,
    const float* W3, const float* b3, const float* W4, const float* b4,
    const float* W5, const float* b5, const float* W6, const float* b6,
    const float* W7, const float* b7, const float* W8, const float* b8,
    const float* lam1p, const float* lam2p, const unsigned* __restrict__ mm,
    float* __restrict__ out) {
  __shared__ float w[LDS_W_FLOATS];
  {
    const float* Wsrc[8] = {W1, W2, W3, W4, W5, W6, W7, W8};
    const float* bsrc[8] = {b1, b2, b3, b4, b5, b6, b7, b8};
    const int dinA[8]  = {3, 3, 20, 20, 20, 20, 20, 20};
    const int doutA[8] = {3, 20, 20, 20, 20, 20, 20, 2};
    const int offW[8]  = {0, 12, 92, 512, 932, 1352, 1772, 2192};
    const int offB[8]  = {9, 72, 492, 912, 1332, 1752, 2172, 2232};
#pragma unroll
    for (int a = 0; a < 8; ++a) {
      const int din = dinA[a], dout = doutA[a], nw = din * dout;
      for (int s = threadIdx.x; s < nw; s += 256) {
        int row = s / dout, col = s % dout;  // compile-time dout -> magic mul
        w[offW[a] + col * din + row] = Wsrc[a][s];  // transposed store
      }
      for (int s = threadIdx.x; s < dout; s += 256) w[offB[a] + s] = bsrc[a][s];
    }
  }

  const int lane = threadIdx.x & 63;
  const int gid  = blockIdx.x * 256 + threadIdx.x;
  const int pt   = gid >> 1;          // point index (two lanes per point)
  const int q    = gid & 1;           // 0: x-family, 1: y-family

  // global min/max: lane l holds block-partial l, butterfly across the wave
  unsigned pmin = mm[2 * lane + 0];
  unsigned pmax = mm[2 * lane + 1];
#pragma unroll
  for (int o = 1; o < 64; o <<= 1) {
    pmin = min(pmin, (unsigned)__shfl_xor((int)pmin, o, 64));
    pmax = max(pmax, (unsigned)__shfl_xor((int)pmax, o, 64));
  }
  float lb = unflip(pmin);
  float ub = unflip(pmax);
  float kk = 2.0f / (ub - lb);

  float x = X[3 * pt], y = X[3 * pt + 1], tt = X[3 * pt + 2];
  float h0 = fmaf(kk, x - lb, -1.0f);
  float h1 = fmaf(kk, y - lb, -1.0f);
  float h2 = fmaf(kk, tt - lb, -1.0f);

  __syncthreads();  // weights staged

  // pass-A / pass-B first-deriv seeds, parity-selected (cndmask, no branch)
  float a0 = q ? 0.0f : kk, a1 = q ? kk : 0.0f;   // pass A: x-dir / y-dir
  float b1s = q ? -kk : kk;                        // pass B: (k,+-k,0)

  float rc1 = 0, rc2 = 0, rc3 = 0, rpv = 0, rpc = 0;  // pass A results
  float s2 = 0, s3 = 0;                                // pass B results

#pragma unroll 1
  for (int ph = 0; ph < 2; ++ph) {
    J3 A[20], O[2];
    float d0 = ph ? kk  : a0;
    float d1 = ph ? b1s : a1;
    A[0].v = h0; A[0].c1 = d0;  A[0].c2 = 0.f; A[0].c3 = 0.f;
    A[1].v = h1; A[1].c1 = d1;  A[1].c2 = 0.f; A[1].c3 = 0.f;
    A[2].v = h2; A[2].c1 = 0.f; A[2].c2 = 0.f; A[2].c3 = 0.f;
    run_net<J3>(w, A, O);
    if (ph == 0) {
      rc1 = O[0].c1; rc2 = O[0].c2; rc3 = O[0].c3;
      rpv = O[1].v;  rpc = O[1].c1;
    } else {
      s2 = O[0].c2; s3 = O[0].c3;
    }
  }

  float rm;
  {
    JM A[20], O[2];
    A[0].v = h0; A[0].a = a0;  A[0].b = 0.f; A[0].m = 0.f;
    A[1].v = h1; A[1].a = a1;  A[1].b = 0.f; A[1].m = 0.f;
    A[2].v = h2; A[2].a = 0.f; A[2].b = kk;  A[2].m = 0.f;
    run_net<JM>(w, A, O);
    rm = O[0].m;   // psi_xt (q=0) / psi_yt (q=1)
  }

  // pair exchange: even lane receives the y-family values
  float psi_y   = __shfl_xor(rc1, 1, 64);
  float psi_yy  = __shfl_xor(rc2, 1, 64);
  float psi_yyy = __shfl_xor(rc3, 1, 64);
  float p_y     = __shfl_xor(rpc, 1, 64);
  float S2m     = __shfl_xor(s2, 1, 64);
  float S3m     = __shfl_xor(s3, 1, 64);
  float psi_yt  = __shfl_xor(rm, 1, 64);

  if (q == 0) {
    float psi_x = rc1, psi_xx = rc2, psi_xxx = rc3;
    float p_val = rpv, p_x = rpc;
    float S2p = s2, S3p = s3;
    float psi_xt = rm;

    // polarization identities
    float psi_xy  = 0.25f * (S2p - S2m);
    float psi_xxy = (S3p - S3m - 2.0f * psi_yyy) * (1.0f / 6.0f);
    float psi_xyy = (S3p + S3m - 2.0f * psi_xxx) * (1.0f / 6.0f);

    float u = psi_y, vv = -psi_x;
    float u_x = psi_xy,  u_y = psi_yy,  u_t = psi_yt;
    float v_x = -psi_xx, v_y = -psi_xy, v_t = -psi_xt;
    float u_xx = psi_xxy,  u_yy = psi_yyy;
    float v_xx = -psi_xxx, v_yy = -psi_xyy;

    float lam1 = lam1p[0], lam2 = lam2p[0];
    float f_u = u_t + lam1 * (u * u_x + vv * u_y) + p_x - lam2 * (u_xx + u_yy);
    float f_v = v_t + lam1 * (u * v_x + vv * v_y) + p_y - lam2 * (v_xx + v_yy);

    out[pt] = u;
    out[NPTS + pt] = vv;
    out[2 * NPTS + pt] = p_val;
    out[3 * NPTS + pt] = f_u;
    out[4 * NPTS + pt] = f_v;
  }
}

extern "C" void kernel_launch(void* const* d_in, const int* in_sizes, int n_in,
                              void* d_out, int out_size, void* d_ws, size_t ws_size,
                              hipStream_t stream) {
  (void)in_sizes; (void)n_in; (void)out_size; (void)ws_size;
  const float* X = (const float*)d_in[0];
  const float* W[8]; const float* B[8];
  for (int i = 0; i < 8; ++i) {
    W[i] = (const float*)d_in[1 + 2 * i];
    B[i] = (const float*)d_in[2 + 2 * i];
  }
  const float* lam1 = (const float*)d_in[17];
  const float* lam2 = (const float*)d_in[18];
  unsigned* mm = (unsigned*)d_ws;
  float* out = (float*)d_out;

  hipLaunchKernelGGL(mm_reduce, dim3(MM_BLOCKS), dim3(256), 0, stream, X, mm);
  hipLaunchKernelGGL(pinn_main, dim3(2 * NPTS / 256), dim3(256), 0, stream,
                     X, W[0], B[0], W[1], B[1], W[2], B[2], W[3], B[3],
                     W[4], B[4], W[5], B[5], W[6], B[6], W[7], B[7],
                     lam1, lam2, mm, out);
}

// Round 5
// 244.430 us; speedup vs baseline: 2.6752x; 1.6602x over previous
//
#include <hip/hip_runtime.h>

#define NPTS 65536
#define MM_BLOCKS 64

// ---------------------------------------------------------------------------
// fast tanh: tanh(x) = 1 - 2/(e^{2x}+1). Saturates correctly at +-inf, no NaN.
// ---------------------------------------------------------------------------
__device__ __forceinline__ float fast_tanh(float x) {
  float e = __expf(2.0f * x);
  float r = __builtin_amdgcn_rcpf(e + 1.0f);
  return fmaf(-2.0f, r, 1.0f);
}

// ---------------------------------------------------------------------------
// Univariate order-3 jet (4 components -- the max that fits registers; the
// 6-comp variant in round 2 spilled 1.5 GB).
// ---------------------------------------------------------------------------
struct J3 {
  float v, c1, c2, c3;
  __device__ __forceinline__ static J3 seed(float bias) {
    J3 z; z.v = bias; z.c1 = 0.f; z.c2 = 0.f; z.c3 = 0.f; return z;
  }
  __device__ __forceinline__ void macc(float w, const J3& o) {
    v  = fmaf(w, o.v,  v);
    c1 = fmaf(w, o.c1, c1);
    c2 = fmaf(w, o.c2, c2);
    c3 = fmaf(w, o.c3, c3);
  }
  __device__ __forceinline__ J3 chain() const {
    float s    = fast_tanh(v);
    float fp   = fmaf(-s, s, 1.0f);             // 1 - s^2
    float fpp  = -2.0f * s * fp;                // -2 s (1-s^2)
    float fppp = fmaf(6.0f * s, s, -2.0f) * fp; // (6 s^2 - 2)(1 - s^2)
    J3 r;
    r.v  = s;
    r.c1 = fp * c1;
    r.c2 = fmaf(fpp, c1 * c1, fp * c2);
    r.c3 = fmaf(fppp * c1, c1 * c1, fmaf(3.0f * fpp, c1 * c2, fp * c3));
    return r;
  }
};

// ---------------------------------------------------------------------------
// Mixed second-order jet: value v, first derivs a (dir A), b (dir B), mixed m.
// ---------------------------------------------------------------------------
struct JM {
  float v, a, b, m;
  __device__ __forceinline__ static JM seed(float bias) {
    JM z; z.v = bias; z.a = 0.f; z.b = 0.f; z.m = 0.f; return z;
  }
  __device__ __forceinline__ void macc(float w, const JM& o) {
    v = fmaf(w, o.v, v);
    a = fmaf(w, o.a, a);
    b = fmaf(w, o.b, b);
    m = fmaf(w, o.m, m);
  }
  __device__ __forceinline__ JM chain() const {
    float s   = fast_tanh(v);
    float fp  = fmaf(-s, s, 1.0f);
    float fpp = -2.0f * s * fp;
    JM r;
    r.v = s;
    r.a = fp * a;
    r.b = fp * b;
    r.m = fmaf(fpp, a * b, fp * m);
    return r;
  }
};

// ---------------------------------------------------------------------------
// One dense layer + tanh over a jet type.  WT TRANSPOSED in LDS so the
// unrolled i-loop reads consecutive floats (ds_read_b128, wave-uniform
// address = broadcast).
// ---------------------------------------------------------------------------
template <class J, int DIN, int DOUT>
__device__ __forceinline__ void layerT(const float* __restrict__ WT,
                                       const float* __restrict__ bias,
                                       const J* in, J* out) {
#pragma unroll
  for (int j = 0; j < DOUT; ++j) {
    J z = J::seed(bias[j]);
#pragma unroll
    for (int i = 0; i < DIN; ++i) z.macc(WT[j * DIN + i], in[i]);
    out[j] = z.chain();
  }
}

// LDS layout (floats): L0 W@0(9) b@9(3) | L1 W@12(60) b@72(20)
// | L2..L6 stride 420: W@92+420l(400) b@+400(20) | L7 W@2192(40) b@2232(2)
#define LDS_W_FLOATS 2234

// ROUND-0 COPY-BACK FORM -- DO NOT "optimize" into explicit ping-pong.
// Empirical A/B across rounds 0/3/4: with ONE layerT<20,20> instance in a
// rolled loop + B->A copy, the allocator keeps both jet arrays in registers
// (2.7 MB spill total).  With THREE unrolled layerT<20,20> instances
// (ping-pong form), it spills the 80-float buffers to scratch: 440 MB-1 GB
// of FETCH+WRITE and occupancy collapse.  The 80 v_movs/iter are noise.
template <class J>
__device__ __forceinline__ void run_net(const float* __restrict__ w, J* A, J* O) {
  J B[20];
  layerT<J, 3, 3>(w + 0, w + 9, A, B);
  layerT<J, 3, 20>(w + 12, w + 72, B, A);
#pragma unroll 1
  for (int l = 0; l < 5; ++l) {   // keep rolled: hot body stays in I-cache
    const float* Wl = w + 92 + l * 420;
    layerT<J, 20, 20>(Wl, Wl + 400, A, B);
#pragma unroll
    for (int jj = 0; jj < 20; ++jj) A[jj] = B[jj];
  }
  layerT<J, 20, 2>(w + 2192, w + 2232, A, O);
}

// ---------------------------------------------------------------------------
// min/max of X[:,0] via monotone-uint keys; one partial pair per block,
// butterfly-reduced per wave inside pinn_main.
// ---------------------------------------------------------------------------
__device__ __forceinline__ unsigned flipk(float f) {
  unsigned u = __float_as_uint(f);
  return (u & 0x80000000u) ? ~u : (u | 0x80000000u);
}
__device__ __forceinline__ float unflip(unsigned k) {
  unsigned u = (k & 0x80000000u) ? (k ^ 0x80000000u) : ~k;
  return __uint_as_float(u);
}

__global__ void __launch_bounds__(256) mm_reduce(const float* __restrict__ X,
                                                 unsigned* __restrict__ mm) {
  __shared__ unsigned smin[4], smax[4];
  unsigned kmin = 0xFFFFFFFFu, kmax = 0u;
  for (int i = blockIdx.x * 256 + threadIdx.x; i < NPTS; i += gridDim.x * 256) {
    unsigned key = flipk(X[3 * i]);
    kmin = min(kmin, key);
    kmax = max(kmax, key);
  }
#pragma unroll
  for (int o = 32; o > 0; o >>= 1) {
    kmin = min(kmin, (unsigned)__shfl_down((int)kmin, o, 64));
    kmax = max(kmax, (unsigned)__shfl_down((int)kmax, o, 64));
  }
  int wv = threadIdx.x >> 6;
  if ((threadIdx.x & 63) == 0) { smin[wv] = kmin; smax[wv] = kmax; }
  __syncthreads();
  if (threadIdx.x == 0) {
    kmin = min(min(smin[0], smin[1]), min(smin[2], smin[3]));
    kmax = max(max(smax[0], smax[1]), max(smax[2], smax[3]));
    mm[2 * blockIdx.x + 0] = kmin;
    mm[2 * blockIdx.x + 1] = kmax;
  }
}

// ---------------------------------------------------------------------------
// Main kernel: TWO THREADS PER POINT, identical code path for every thread
// (pass seeds are DATA selected by lane parity q -- no divergence).  Each
// thread runs 3 sequential 4-comp passes; 2048 waves = 2 waves/SIMD target.
// PLAIN __launch_bounds__(256) (256-VGPR cap, pool 512/SIMD -> 2 waves).
// (256,2) capped at 128 VGPR -> 1 GB spills (round 3); (256,1) let 6-comp
// jets blow past 256 -> 1.5 GB spills (round 2).  run_net MUST stay in the
// copy-back form (see comment there).
//   q=0: J3 d=(k,0,0) -> psi_x,psi_xx,psi_xxx,p,p_x; J3 d=(k,k,0) -> S2p,S3p;
//        JM a=x,b=t -> psi_xt
//   q=1: J3 d=(0,k,0) -> psi_y,psi_yy,psi_yyy,p_y;   J3 d=(k,-k,0) -> S2m,S3m;
//        JM a=y,b=t -> psi_yt
// Pair combine: 7 shfl_xor(...,1), even lane assembles + stores.
// ---------------------------------------------------------------------------
__global__ void __launch_bounds__(256) pinn_main(
    const float* __restrict__ X,
    const float* W1, const float* b1, const float* W2, const float* b2,
    const float* W3, const float* b3, const float* W4, const float* b4,
    const float* W5, const float* b5, const float* W6, const float* b6,
    const float* W7, const float* b7, const float* W8, const float* b8,
    const float* lam1p, const float* lam2p, const unsigned* __restrict__ mm,
    float* __restrict__ out) {
  __shared__ float w[LDS_W_FLOATS];
  {
    const float* Wsrc[8] = {W1, W2, W3, W4, W5, W6, W7, W8};
    const float* bsrc[8] = {b1, b2, b3, b4, b5, b6, b7, b8};
    const int dinA[8]  = {3, 3, 20, 20, 20, 20, 20, 20};
    const int doutA[8] = {3, 20, 20, 20, 20, 20, 20, 2};
    const int offW[8]  = {0, 12, 92, 512, 932, 1352, 1772, 2192};
    const int offB[8]  = {9, 72, 492, 912, 1332, 1752, 2172, 2232};
#pragma unroll
    for (int a = 0; a < 8; ++a) {
      const int din = dinA[a], dout = doutA[a], nw = din * dout;
      for (int s = threadIdx.x; s < nw; s += 256) {
        int row = s / dout, col = s % dout;  // compile-time dout -> magic mul
        w[offW[a] + col * din + row] = Wsrc[a][s];  // transposed store
      }
      for (int s = threadIdx.x; s < dout; s += 256) w[offB[a] + s] = bsrc[a][s];
    }
  }

  const int lane = threadIdx.x & 63;
  const int gid  = blockIdx.x * 256 + threadIdx.x;
  const int pt   = gid >> 1;          // point index (two lanes per point)
  const int q    = gid & 1;           // 0: x-family, 1: y-family

  // global min/max: lane l holds block-partial l, butterfly across the wave
  unsigned pmin = mm[2 * lane + 0];
  unsigned pmax = mm[2 * lane + 1];
#pragma unroll
  for (int o = 1; o < 64; o <<= 1) {
    pmin = min(pmin, (unsigned)__shfl_xor((int)pmin, o, 64));
    pmax = max(pmax, (unsigned)__shfl_xor((int)pmax, o, 64));
  }
  float lb = unflip(pmin);
  float ub = unflip(pmax);
  float kk = 2.0f / (ub - lb);

  float x = X[3 * pt], y = X[3 * pt + 1], tt = X[3 * pt + 2];
  float h0 = fmaf(kk, x - lb, -1.0f);
  float h1 = fmaf(kk, y - lb, -1.0f);
  float h2 = fmaf(kk, tt - lb, -1.0f);

  __syncthreads();  // weights staged

  // pass-A / pass-B first-deriv seeds, parity-selected (cndmask, no branch)
  float a0 = q ? 0.0f : kk, a1 = q ? kk : 0.0f;   // pass A: x-dir / y-dir
  float b1s = q ? -kk : kk;                        // pass B: (k,+-k,0)

  float rc1 = 0, rc2 = 0, rc3 = 0, rpv = 0, rpc = 0;  // pass A results
  float s2 = 0, s3 = 0;                                // pass B results

#pragma unroll 1
  for (int ph = 0; ph < 2; ++ph) {
    J3 A[20], O[2];
    float d0 = ph ? kk  : a0;
    float d1 = ph ? b1s : a1;
    A[0].v = h0; A[0].c1 = d0;  A[0].c2 = 0.f; A[0].c3 = 0.f;
    A[1].v = h1; A[1].c1 = d1;  A[1].c2 = 0.f; A[1].c3 = 0.f;
    A[2].v = h2; A[2].c1 = 0.f; A[2].c2 = 0.f; A[2].c3 = 0.f;
    run_net<J3>(w, A, O);
    if (ph == 0) {
      rc1 = O[0].c1; rc2 = O[0].c2; rc3 = O[0].c3;
      rpv = O[1].v;  rpc = O[1].c1;
    } else {
      s2 = O[0].c2; s3 = O[0].c3;
    }
  }

  float rm;
  {
    JM A[20], O[2];
    A[0].v = h0; A[0].a = a0;  A[0].b = 0.f; A[0].m = 0.f;
    A[1].v = h1; A[1].a = a1;  A[1].b = 0.f; A[1].m = 0.f;
    A[2].v = h2; A[2].a = 0.f; A[2].b = kk;  A[2].m = 0.f;
    run_net<JM>(w, A, O);
    rm = O[0].m;   // psi_xt (q=0) / psi_yt (q=1)
  }

  // pair exchange: even lane receives the y-family values
  float psi_y   = __shfl_xor(rc1, 1, 64);
  float psi_yy  = __shfl_xor(rc2, 1, 64);
  float psi_yyy = __shfl_xor(rc3, 1, 64);
  float p_y     = __shfl_xor(rpc, 1, 64);
  float S2m     = __shfl_xor(s2, 1, 64);
  float S3m     = __shfl_xor(s3, 1, 64);
  float psi_yt  = __shfl_xor(rm, 1, 64);

  if (q == 0) {
    float psi_x = rc1, psi_xx = rc2, psi_xxx = rc3;
    float p_val = rpv, p_x = rpc;
    float S2p = s2, S3p = s3;
    float psi_xt = rm;

    // polarization identities
    float psi_xy  = 0.25f * (S2p - S2m);
    float psi_xxy = (S3p - S3m - 2.0f * psi_yyy) * (1.0f / 6.0f);
    float psi_xyy = (S3p + S3m - 2.0f * psi_xxx) * (1.0f / 6.0f);

    float u = psi_y, vv = -psi_x;
    float u_x = psi_xy,  u_y = psi_yy,  u_t = psi_yt;
    float v_x = -psi_xx, v_y = -psi_xy, v_t = -psi_xt;
    float u_xx = psi_xxy,  u_yy = psi_yyy;
    float v_xx = -psi_xxx, v_yy = -psi_xyy;

    float lam1 = lam1p[0], lam2 = lam2p[0];
    float f_u = u_t + lam1 * (u * u_x + vv * u_y) + p_x - lam2 * (u_xx + u_yy);
    float f_v = v_t + lam1 * (u * v_x + vv * v_y) + p_y - lam2 * (v_xx + v_yy);

    out[pt] = u;
    out[NPTS + pt] = vv;
    out[2 * NPTS + pt] = p_val;
    out[3 * NPTS + pt] = f_u;
    out[4 * NPTS + pt] = f_v;
  }
}

extern "C" void kernel_launch(void* const* d_in, const int* in_sizes, int n_in,
                              void* d_out, int out_size, void* d_ws, size_t ws_size,
                              hipStream_t stream) {
  (void)in_sizes; (void)n_in; (void)out_size; (void)ws_size;
  const float* X = (const float*)d_in[0];
  const float* W[8]; const float* B[8];
  for (int i = 0; i < 8; ++i) {
    W[i] = (const float*)d_in[1 + 2 * i];
    B[i] = (const float*)d_in[2 + 2 * i];
  }
  const float* lam1 = (const float*)d_in[17];
  const float* lam2 = (const float*)d_in[18];
  unsigned* mm = (unsigned*)d_ws;
  float* out = (float*)d_out;

  hipLaunchKernelGGL(mm_reduce, dim3(MM_BLOCKS), dim3(256), 0, stream, X, mm);
  hipLaunchKernelGGL(pinn_main, dim3(2 * NPTS / 256), dim3(256), 0, stream,
                     X, W[0], B[0], W[1], B[1], W[2], B[2], W[3], B[3],
                     W[4], B[4], W[5], B[5], W[6], B[6], W[7], B[7],
                     lam1, lam2, mm, out);
}